// Round 5
// baseline (85.141 us; speedup 1.0000x reference)
//
#include <hip/hip_runtime.h>
#include <hip/hip_bf16.h>

#define SQ 2048
#define NBATCH 2
#define NHEAD 16
#define DHEAD 128
#define NKT 32                       // 2048/64 KV tiles
#define NQT 16                       // 2048/128 Q tiles
#define SCALE_L2E 0.1275174609f      // (1/sqrt(128)) * log2(e)
#define LOG2E 1.4426950408889634f
#define DEFER_THR 11.0f              // ~8 nats, in log2 units

typedef _Float16 f16x8 __attribute__((ext_vector_type(8)));
typedef _Float16 f16x4 __attribute__((ext_vector_type(4)));
typedef __fp16 fp16x2 __attribute__((ext_vector_type(2)));
typedef float f32x4 __attribute__((ext_vector_type(4)));
typedef float f32x16 __attribute__((ext_vector_type(16)));
typedef unsigned int u32x4 __attribute__((ext_vector_type(4)));

static __device__ __forceinline__ _Float16 f2h(float f) { return (_Float16)f; }

static __device__ __forceinline__ unsigned int pkrtz(float a, float b) {
    fp16x2 h = __builtin_amdgcn_cvt_pkrtz(a, b);
    return __builtin_bit_cast(unsigned int, h);
}

// ---------------------------------------------------------------------------
// Pre-pass (unchanged layouts): K -> fp16 [b][kt][64][128] swizzled,
//                               V -> fp16 transposed [b][kt][128][64] swizzled
// ---------------------------------------------------------------------------
__global__ __launch_bounds__(256)
void prepack(const float* __restrict__ k, const float* __restrict__ v,
             _Float16* __restrict__ kws, _Float16* __restrict__ vws) {
    const int tile  = blockIdx.x;        // 0..127
    const int which = tile >> 6;         // 0 = K, 1 = V
    const int b     = (tile >> 5) & 1;
    const int kt    = tile & 31;
    const int tid   = threadIdx.x;

    if (which == 0) {
        const float* kbase = k + (size_t)b * DHEAD + (size_t)kt * 64 * (NBATCH * DHEAD);
        _Float16* dst = kws + ((size_t)b * NKT + kt) * 8192;
        #pragma unroll
        for (int p = 0; p < 8; ++p) {
            const int id4 = tid + p * 256;
            const int row = id4 >> 5;
            const int c0  = (id4 & 31) << 2;
            f32x4 a = *(const f32x4*)(kbase + (size_t)row * (NBATCH * DHEAD) + c0);
            const int e = (row * 128 + c0) ^ ((row & 7) << 3);
            f16x4 pk = { f2h(a.x), f2h(a.y), f2h(a.z), f2h(a.w) };
            *(f16x4*)(dst + e) = pk;
        }
    } else {
        const float* vbase = v + (size_t)b * DHEAD;
        _Float16* dst = vws + ((size_t)b * NKT + kt) * 8192;
        const int d    = tid & 127;
        const int half = tid >> 7;
        #pragma unroll
        for (int p = 0; p < 8; ++p) {
            const int c0 = (p * 2 + half) * 4;
            float a0 = vbase[(size_t)(kt * 64 + c0 + 0) * (NBATCH * DHEAD) + d];
            float a1 = vbase[(size_t)(kt * 64 + c0 + 1) * (NBATCH * DHEAD) + d];
            float a2 = vbase[(size_t)(kt * 64 + c0 + 2) * (NBATCH * DHEAD) + d];
            float a3 = vbase[(size_t)(kt * 64 + c0 + 3) * (NBATCH * DHEAD) + d];
            const int e = (d * 64 + c0) ^ ((d & 7) << 3);
            f16x4 pk = { f2h(a0), f2h(a1), f2h(a2), f2h(a3) };
            *(f16x4*)(dst + e) = pk;
        }
    }
}

static __device__ __forceinline__ void gload16(const _Float16* gsrc, _Float16* ldst) {
    __builtin_amdgcn_global_load_lds(
        (const __attribute__((address_space(1))) void*)gsrc,
        (__attribute__((address_space(3))) void*)ldst, 16, 0, 0);
}

// ---------------------------------------------------------------------------
// Hot kernel: 4 waves x 32 q-rows (128-row blocks), 32x32x16 MFMA,
// in-register P (cvt_pkrtz + permlane32_swap), O^T accumulation.
// ---------------------------------------------------------------------------
__global__ __launch_bounds__(256)
void attn_fwd(const float* __restrict__ q, const _Float16* __restrict__ kws,
              const _Float16* __restrict__ vws, const float* __restrict__ sinks,
              float* __restrict__ out) {
    __shared__ _Float16 Kb[2][8192];     // 64x128 swizzled
    __shared__ _Float16 Vb[2][8192];     // 128x64 (V^T) swizzled

    const int tid  = threadIdx.x;
    const int w    = tid >> 6;
    const int lane = tid & 63;
    const int qc   = lane & 31;          // q column (lane-local stats!)
    const int h2   = lane >> 5;

    const int bid = blockIdx.x;
    const int b   = bid & 1;
    const int h   = (bid >> 1) & 15;
    const int qt  = (NQT - 1) - (bid >> 5);   // heavy blocks first
    const int q0  = qt * 128;
    const int sq  = q0 + w * 32 + qc;

    // ---- Q fragments (B-operand): col=qc, k(d) = 16*ks + 8*h2 + j ----
    f16x8 qf[8];
    {
        const float* qrow = q + ((size_t)sq * NBATCH + b) * (NHEAD * DHEAD) + h * DHEAD;
        #pragma unroll
        for (int ks = 0; ks < 8; ++ks) {
            const int d0 = ks * 16 + h2 * 8;
            f32x4 a = *(const f32x4*)(qrow + d0);
            f32x4 c = *(const f32x4*)(qrow + d0 + 4);
            f16x8 t;
            t[0] = f2h(a.x * SCALE_L2E); t[1] = f2h(a.y * SCALE_L2E);
            t[2] = f2h(a.z * SCALE_L2E); t[3] = f2h(a.w * SCALE_L2E);
            t[4] = f2h(c.x * SCALE_L2E); t[5] = f2h(c.y * SCALE_L2E);
            t[6] = f2h(c.z * SCALE_L2E); t[7] = f2h(c.w * SCALE_L2E);
            qf[ks] = t;
        }
    }

    float m_run = sinks[h] * LOG2E;   // base-2 logit space
    float l_run = 1.0f;               // sink contribution
    f32x16 acc[4];                    // O^T: col=q(lane-local), rows=d
    #pragma unroll
    for (int i = 0; i < 4; ++i) acc[i] = (f32x16)(0.0f);

    const _Float16* ktiles = kws + (size_t)b * NKT * 8192;
    const _Float16* vtiles = vws + (size_t)b * NKT * 8192;
    const int ntiles = 2 * qt + 2;

    // prologue: stage tile 0
    #pragma unroll
    for (int j = 0; j < 4; ++j) {
        const int off = (w * 4 + j) * 512;
        gload16(ktiles + off + lane * 8, &Kb[0][off]);
        gload16(vtiles + off + lane * 8, &Vb[0][off]);
    }
    asm volatile("s_waitcnt vmcnt(0)" ::: "memory");
    __builtin_amdgcn_s_barrier();

    for (int it = 0; it < ntiles; ++it) {
        const int cur = it & 1;
        if (it + 1 < ntiles) {
            const _Float16* kt_n = ktiles + (size_t)(it + 1) * 8192;
            const _Float16* vt_n = vtiles + (size_t)(it + 1) * 8192;
            #pragma unroll
            for (int j = 0; j < 4; ++j) {
                const int off = (w * 4 + j) * 512;
                gload16(kt_n + off + lane * 8, &Kb[cur ^ 1][off]);
                gload16(vt_n + off + lane * 8, &Vb[cur ^ 1][off]);
            }
        }

        const int ktbase = it * 64;
        if (ktbase <= q0 + w * 32 + 31) {   // wave has live rows in this tile
            // ---- S^T = K * Q^T : col=q=qc, row=kv=(i&3)+8*(i>>2)+4*h2+32*mt ----
            f32x16 sa0 = (f32x16)(0.0f), sa1 = (f32x16)(0.0f);
            #pragma unroll
            for (int ks = 0; ks < 8; ++ks) {
                const int col = ks * 16 + h2 * 8;
                const int e0 = (qc * 128 + col) ^ ((qc & 7) << 3);
                const int e1 = ((32 + qc) * 128 + col) ^ ((qc & 7) << 3);
                f16x8 k0 = *(const f16x8*)(&Kb[cur][e0]);
                f16x8 k1 = *(const f16x8*)(&Kb[cur][e1]);
                sa0 = __builtin_amdgcn_mfma_f32_32x32x16_f16(k0, qf[ks], sa0, 0, 0, 0);
                sa1 = __builtin_amdgcn_mfma_f32_32x32x16_f16(k1, qf[ks], sa1, 0, 0, 0);
            }

            float sv[32];
            #pragma unroll
            for (int i = 0; i < 16; ++i) { sv[i] = sa0[i]; sv[16 + i] = sa1[i]; }

            // ---- causal mask (wave-uniform branch; only near-diagonal tiles) ----
            if (ktbase + 63 > q0 + w * 32) {
                #pragma unroll
                for (int mt = 0; mt < 2; ++mt)
                    #pragma unroll
                    for (int i = 0; i < 16; ++i) {
                        const int tk = ktbase + (i & 3) + 8 * (i >> 2) + 4 * h2 + 32 * mt;
                        if (tk > sq) sv[mt * 16 + i] = -1e30f;
                    }
            }

            // ---- online softmax (base-2, lane-local stats for q=qc) ----
            float mx = sv[0];
            #pragma unroll
            for (int i = 1; i < 32; ++i) mx = fmaxf(mx, sv[i]);
            mx = fmaxf(mx, __shfl_xor(mx, 32));

            if (!__all(mx <= m_run + DEFER_THR)) {   // defer-max (T13)
                const float mnew = fmaxf(m_run, mx);
                const float corr = __builtin_amdgcn_exp2f(m_run - mnew);
                m_run = mnew;
                l_run *= corr;
                #pragma unroll
                for (int mt = 0; mt < 4; ++mt) acc[mt] *= corr;
            }

            float ls = 0.0f;
            #pragma unroll
            for (int i = 0; i < 32; ++i) {
                const float p = __builtin_amdgcn_exp2f(sv[i] - m_run);
                sv[i] = p;
                ls += p;
            }
            ls += __shfl_xor(ls, 32);
            l_run += ls;

            // ---- P -> f16 A-frags in-register (cvt_pkrtz + permlane32_swap) ----
            unsigned int pw[4][4];
            #pragma unroll
            for (int mt = 0; mt < 2; ++mt) {
                unsigned int e0[4], e1[4];
                #pragma unroll
                for (int bq = 0; bq < 4; ++bq) {
                    e0[bq] = pkrtz(sv[mt * 16 + 4 * bq + 0], sv[mt * 16 + 4 * bq + 1]);
                    e1[bq] = pkrtz(sv[mt * 16 + 4 * bq + 2], sv[mt * 16 + 4 * bq + 3]);
                }
                #pragma unroll
                for (int kl = 0; kl < 2; ++kl) {
                    unsigned int a0 = e0[2 * kl], b0 = e0[2 * kl + 1];
                    unsigned int a1 = e1[2 * kl], b1 = e1[2 * kl + 1];
                    asm volatile("v_permlane32_swap_b32 %0, %1" : "+v"(a0), "+v"(b0));
                    asm volatile("v_permlane32_swap_b32 %0, %1" : "+v"(a1), "+v"(b1));
                    pw[mt * 2 + kl][0] = a0; pw[mt * 2 + kl][1] = a1;
                    pw[mt * 2 + kl][2] = b0; pw[mt * 2 + kl][3] = b1;
                }
            }

            // ---- O^T += V^T * P^T ----
            #pragma unroll
            for (int ks = 0; ks < 4; ++ks) {
                u32x4 pu = { pw[ks][0], pw[ks][1], pw[ks][2], pw[ks][3] };
                f16x8 pf = __builtin_bit_cast(f16x8, pu);
                #pragma unroll
                for (int mt = 0; mt < 4; ++mt) {
                    const int d = mt * 32 + qc;
                    const int e = (d * 64 + ks * 16 + h2 * 8) ^ ((qc & 7) << 3);
                    f16x8 vf = *(const f16x8*)(&Vb[cur][e]);
                    acc[mt] = __builtin_amdgcn_mfma_f32_32x32x16_f16(vf, pf, acc[mt], 0, 0, 0);
                }
            }
        }

        asm volatile("s_waitcnt vmcnt(0)" ::: "memory");
        __builtin_amdgcn_s_barrier();
    }

    // ---- epilogue: lane-local normalize, f32x4 stores ----
    const float rl = 1.0f / l_run;
    float* orow = out + ((size_t)sq * NBATCH + b) * (NHEAD * DHEAD) + h * DHEAD;
    #pragma unroll
    for (int mt = 0; mt < 4; ++mt)
        #pragma unroll
        for (int rg = 0; rg < 4; ++rg) {
            f32x4 o = { acc[mt][4 * rg + 0] * rl, acc[mt][4 * rg + 1] * rl,
                        acc[mt][4 * rg + 2] * rl, acc[mt][4 * rg + 3] * rl };
            *(f32x4*)(orow + mt * 32 + rg * 8 + h2 * 4) = o;
        }
}

extern "C" void kernel_launch(void* const* d_in, const int* in_sizes, int n_in,
                              void* d_out, int out_size, void* d_ws, size_t ws_size,
                              hipStream_t stream) {
    const float* q     = (const float*)d_in[0];
    const float* k     = (const float*)d_in[1];
    const float* v     = (const float*)d_in[2];
    const float* sinks = (const float*)d_in[3];
    float* out = (float*)d_out;

    _Float16* kws = (_Float16*)d_ws;                        // 1 MB
    _Float16* vws = kws + (size_t)NBATCH * NKT * 8192;      // 1 MB

    prepack<<<dim3(128), 256, 0, stream>>>(k, v, kws, vws);
    attn_fwd<<<dim3(NQT * NBATCH * NHEAD), 256, 0, stream>>>(q, kws, vws, sinks, out);
}